// Round 7
// baseline (458.175 us; speedup 1.0000x reference)
//
#include <hip/hip_runtime.h>
#include <hip/hip_bf16.h>

// ROUND 7: I/O-contract fix — inputs f32, OUTPUT f32 (reference returns f32;
// prior rounds wrote bf16 into an f32 buffer => ~1.82 mismatch signature).
// Internals bf16 MFMA (validated R2<=>R4<=>R5 cross-agreement).
// B=2 T=2048 C=1024 H=16 D=64.
// ws (bf16): q[4M] k[4M] v[4M] ([B,H,T,D]) + attn_out[4M] ([B,T,C]) = 32MB.

typedef __attribute__((ext_vector_type(8))) short bf16x8;
typedef __attribute__((ext_vector_type(4))) short bf16x4;
typedef __attribute__((ext_vector_type(4))) float floatx4;

#define MFMA16(a, b, c) __builtin_amdgcn_mfma_f32_16x16x32_bf16((a), (b), (c), 0, 0, 0)

static constexpr int Bc = 2, Tc = 2048, Cc = 1024, Hc = 16, Dc = 64;
static constexpr size_t QKV_STRIDE = (size_t)Bc * Hc * Tc * Dc; // 4194304
static constexpr float NEG_BIG = -3.0e38f;

__device__ __forceinline__ bf16x8 load8(const __hip_bfloat16* p) {
    return *(const bf16x8*)p;
}

// LDS fragment load as two 8B halves (stride-72 rows are 8B aligned).
__device__ __forceinline__ bf16x8 load8_lds(const __hip_bfloat16* p) {
    const bf16x4 lo = *(const bf16x4*)p;
    const bf16x4 hi = *(const bf16x4*)(p + 4);
    bf16x8 r;
    r[0] = lo[0]; r[1] = lo[1]; r[2] = lo[2]; r[3] = lo[3];
    r[4] = hi[0]; r[5] = hi[1]; r[6] = hi[2]; r[7] = hi[3];
    return r;
}

__device__ __forceinline__ short f2b(float x) {
    union { __hip_bfloat16 h; short s; } u;
    u.h = __float2bfloat16(x);
    return u.s;
}

// Load 8 consecutive f32 (16B-aligned), convert to bf16x8 fragment.
__device__ __forceinline__ bf16x8 cvt8(const float* p) {
    const floatx4 a = *(const floatx4*)p;
    const floatx4 b = *(const floatx4*)(p + 4);
    bf16x8 r;
    r[0] = f2b(a[0]); r[1] = f2b(a[1]); r[2] = f2b(a[2]); r[3] = f2b(a[3]);
    r[4] = f2b(b[0]); r[5] = f2b(b[1]); r[6] = f2b(b[2]); r[7] = f2b(b[3]);
    return r;
}

// ---------------- GEMM1: qkv = x @ w_qkv^T, scatter to q/k/v [B,H,T,D] ------
__global__ __launch_bounds__(256) void gemm_qkv(
    const float* __restrict__ x,
    const float* __restrict__ w,
    __hip_bfloat16* __restrict__ qkv) {
    const int K = Cc;
    const int lane = threadIdx.x & 63;
    const int wave = threadIdx.x >> 6;
    const int waveM = wave >> 1, waveN = wave & 1;
    const int mBase = blockIdx.x * 128 + waveM * 64;
    const int nBase = blockIdx.y * 128 + waveN * 64;
    const int idx16 = lane & 15;
    const int quad = lane >> 4;

    floatx4 acc[4][4] = {};
    const float* aPtr = x + (size_t)(mBase + idx16) * K + quad * 8;
    const float* bPtr = w + (size_t)(nBase + idx16) * K + quad * 8;

    for (int k0 = 0; k0 < K; k0 += 32) {
        bf16x8 a[4], b[4];
#pragma unroll
        for (int i = 0; i < 4; i++) a[i] = cvt8(aPtr + (size_t)i * 16 * K + k0);
#pragma unroll
        for (int j = 0; j < 4; j++) b[j] = cvt8(bPtr + (size_t)j * 16 * K + k0);
#pragma unroll
        for (int i = 0; i < 4; i++)
#pragma unroll
            for (int j = 0; j < 4; j++)
                acc[i][j] = MFMA16(a[i], b[j], acc[i][j]);
    }

#pragma unroll
    for (int i = 0; i < 4; i++) {
#pragma unroll
        for (int j = 0; j < 4; j++) {
            const int n = nBase + j * 16 + idx16;
            const int part = n >> 10;
            const int rem = n & 1023;
            const int h = rem >> 6, d = rem & 63;
#pragma unroll
            for (int r = 0; r < 4; r++) {
                const int m = mBase + i * 16 + quad * 4 + r;
                const int bb = m >> 11, t = m & 2047;
                const size_t o = (size_t)part * QKV_STRIDE +
                                 (((size_t)(bb * Hc + h)) * Tc + t) * Dc + d;
                qkv[o] = __float2bfloat16(acc[i][j][r]);
            }
        }
    }
}

// ---------------- GEMM2: out(f32) = attn_out(bf16) @ w_proj^T(f32) ----------
__global__ __launch_bounds__(256) void gemm_proj(
    const __hip_bfloat16* __restrict__ a_in,
    const float* __restrict__ w,
    float* __restrict__ out) {
    const int K = Cc;
    const int lane = threadIdx.x & 63;
    const int wave = threadIdx.x >> 6;
    const int waveM = wave >> 1, waveN = wave & 1;
    const int mBase = blockIdx.x * 128 + waveM * 64;
    const int nBase = blockIdx.y * 128 + waveN * 64;
    const int idx16 = lane & 15;
    const int quad = lane >> 4;

    floatx4 acc[4][4] = {};
    const __hip_bfloat16* aPtr = a_in + (size_t)(mBase + idx16) * K + quad * 8;
    const float* bPtr = w + (size_t)(nBase + idx16) * K + quad * 8;

    for (int k0 = 0; k0 < K; k0 += 32) {
        bf16x8 a[4], b[4];
#pragma unroll
        for (int i = 0; i < 4; i++) a[i] = load8(aPtr + (size_t)i * 16 * K + k0);
#pragma unroll
        for (int j = 0; j < 4; j++) b[j] = cvt8(bPtr + (size_t)j * 16 * K + k0);
#pragma unroll
        for (int i = 0; i < 4; i++)
#pragma unroll
            for (int j = 0; j < 4; j++)
                acc[i][j] = MFMA16(a[i], b[j], acc[i][j]);
    }

    // f32 output: out[m][n]
#pragma unroll
    for (int i = 0; i < 4; i++) {
#pragma unroll
        for (int j = 0; j < 4; j++) {
            const int n = nBase + j * 16 + idx16;
#pragma unroll
            for (int r = 0; r < 4; r++) {
                const int m = mBase + i * 16 + quad * 4 + r;
                out[(size_t)m * Cc + n] = acc[i][j][r];
            }
        }
    }
}

// ---------------- Flash attention (R3 structure, validated vs naive) --------
__global__ __launch_bounds__(256) void attn_kernel(
    const __hip_bfloat16* __restrict__ qkv,
    __hip_bfloat16* __restrict__ aout) {
    __shared__ __hip_bfloat16 lds_p[4][16][72];
    __shared__ __hip_bfloat16 lds_vt[64][72];

    const int lane = threadIdx.x & 63;
    const int wave = threadIdx.x >> 6;
    const int col = lane & 15;
    const int quad = lane >> 4;
    const int qt = blockIdx.x;
    const int h = blockIdx.y;
    const int b = blockIdx.z;
    const int qBase = qt * 64;

    const size_t headOff = ((size_t)(b * Hc + h)) * Tc * Dc;
    const __hip_bfloat16* qp = qkv + headOff;
    const __hip_bfloat16* kp = qkv + QKV_STRIDE + headOff;
    const __hip_bfloat16* vp = qkv + 2 * QKV_STRIDE + headOff;

    const int qrow = qBase + wave * 16 + col;
    bf16x8 qf[2];
    qf[0] = load8(qp + (size_t)qrow * Dc + quad * 8);
    qf[1] = load8(qp + (size_t)qrow * Dc + 32 + quad * 8);

    floatx4 o_acc[4] = {};
    float mrow[4], lrow[4];
#pragma unroll
    for (int r = 0; r < 4; r++) { mrow[r] = NEG_BIG; lrow[r] = 0.f; }
    const float scale = 0.125f;
    const int q0 = qBase + wave * 16 + quad * 4;

    const int nkt = qt + 1;
    for (int kt = 0; kt < nkt; kt++) {
        const int keyBase = kt * 64;

        __syncthreads();
#pragma unroll
        for (int i = 0; i < 16; i++) {
            const int e = i * 256 + threadIdx.x;
            const int kl = e >> 6, d = e & 63;
            lds_vt[d][kl] = vp[((size_t)(keyBase + kl)) * Dc + d];
        }
        __syncthreads();

        floatx4 s[4];
#pragma unroll
        for (int j = 0; j < 4; j++) {
            floatx4 acc = {0.f, 0.f, 0.f, 0.f};
            const int key = keyBase + j * 16 + col;
            const bf16x8 k0 = load8(kp + (size_t)key * Dc + quad * 8);
            const bf16x8 k1 = load8(kp + (size_t)key * Dc + 32 + quad * 8);
            acc = MFMA16(qf[0], k0, acc);
            acc = MFMA16(qf[1], k1, acc);
            s[j] = acc;
        }

        float pm[4];
#pragma unroll
        for (int r = 0; r < 4; r++) pm[r] = NEG_BIG;
#pragma unroll
        for (int j = 0; j < 4; j++) {
            const int key = keyBase + j * 16 + col;
#pragma unroll
            for (int r = 0; r < 4; r++) {
                float v = s[j][r] * scale;
                if (key > q0 + r) v = NEG_BIG;
                s[j][r] = v;
                pm[r] = fmaxf(pm[r], v);
            }
        }
#pragma unroll
        for (int off = 1; off < 16; off <<= 1)
#pragma unroll
            for (int r = 0; r < 4; r++)
                pm[r] = fmaxf(pm[r], __shfl_xor(pm[r], off, 64));

        float alpha[4];
#pragma unroll
        for (int r = 0; r < 4; r++) {
            const float mnew = fmaxf(mrow[r], pm[r]);
            alpha[r] = __expf(mrow[r] - mnew);
            mrow[r] = mnew;
        }

        float ps[4];
#pragma unroll
        for (int r = 0; r < 4; r++) ps[r] = 0.f;
#pragma unroll
        for (int j = 0; j < 4; j++) {
#pragma unroll
            for (int r = 0; r < 4; r++) {
                const float p = __expf(s[j][r] - mrow[r]);
                ps[r] += p;
                lds_p[wave][quad * 4 + r][j * 16 + col] = __float2bfloat16(p);
            }
        }
#pragma unroll
        for (int off = 1; off < 16; off <<= 1)
#pragma unroll
            for (int r = 0; r < 4; r++)
                ps[r] += __shfl_xor(ps[r], off, 64);
#pragma unroll
        for (int r = 0; r < 4; r++) lrow[r] = lrow[r] * alpha[r] + ps[r];
#pragma unroll
        for (int j = 0; j < 4; j++)
#pragma unroll
            for (int r = 0; r < 4; r++) o_acc[j][r] *= alpha[r];

        bf16x8 pf[2];
        pf[0] = load8_lds(&lds_p[wave][col][quad * 8]);
        pf[1] = load8_lds(&lds_p[wave][col][32 + quad * 8]);
#pragma unroll
        for (int j = 0; j < 4; j++) {
            const bf16x8 v0 = load8_lds(&lds_vt[j * 16 + col][quad * 8]);
            const bf16x8 v1 = load8_lds(&lds_vt[j * 16 + col][32 + quad * 8]);
            o_acc[j] = MFMA16(pf[0], v0, o_acc[j]);
            o_acc[j] = MFMA16(pf[1], v1, o_acc[j]);
        }
    }

#pragma unroll
    for (int j = 0; j < 4; j++) {
        const int d = j * 16 + col;
#pragma unroll
        for (int r = 0; r < 4; r++) {
            const int t = qBase + wave * 16 + quad * 4 + r;
            const size_t o = ((size_t)(b * Tc + t)) * Cc + h * 64 + d;
            aout[o] = __float2bfloat16(o_acc[j][r] / lrow[r]);
        }
    }
}

extern "C" void kernel_launch(void* const* d_in, const int* in_sizes, int n_in,
                              void* d_out, int out_size, void* d_ws, size_t ws_size,
                              hipStream_t stream) {
    // Inputs by element count (all f32): x=4194304, w_qkv=3145728, w_proj=1048576.
    const float* x = nullptr;
    const float* w_qkv = nullptr;
    const float* w_proj = nullptr;
    for (int i = 0; i < n_in; i++) {
        if (in_sizes[i] == 4194304) x = (const float*)d_in[i];
        else if (in_sizes[i] == 3145728) w_qkv = (const float*)d_in[i];
        else if (in_sizes[i] == 1048576) w_proj = (const float*)d_in[i];
    }
    float* out = (float*)d_out;   // reference output dtype = float32

    __hip_bfloat16* qkv = (__hip_bfloat16*)d_ws;            // 3 * 4M bf16
    __hip_bfloat16* attn_out = qkv + 3 * QKV_STRIDE;        // 4M bf16

    gemm_qkv<<<dim3(4096 / 128, 3072 / 128), 256, 0, stream>>>(x, w_qkv, qkv);
    attn_kernel<<<dim3(Tc / 64, Hc, Bc), 256, 0, stream>>>(qkv, attn_out);
    gemm_proj<<<dim3(4096 / 128, 1024 / 128), 256, 0, stream>>>(attn_out, w_proj, out);
}

// Round 8
// 307.561 us; speedup vs baseline: 1.4897x; 1.4897x over previous
//
#include <hip/hip_runtime.h>
#include <hip/hip_bf16.h>

// ROUND 8: m97-style GEMMs (global_load_lds width-16 staging, 2-barrier K-loop,
// XOR chunk swizzle to kill LDS bank conflicts). Attention unchanged from R7.
// Inputs f32, output f32, internals bf16 MFMA.
// ws (bf16): q[4M] k[4M] v[4M] ([B,H,T,D]) + attn_out[4M] ([B,T,C]) = 32MB.

typedef __attribute__((ext_vector_type(8))) short bf16x8;
typedef __attribute__((ext_vector_type(4))) short bf16x4;
typedef __attribute__((ext_vector_type(4))) float floatx4;

#define MFMA16(a, b, c) __builtin_amdgcn_mfma_f32_16x16x32_bf16((a), (b), (c), 0, 0, 0)

static constexpr int Bc = 2, Tc = 2048, Cc = 1024, Hc = 16, Dc = 64;
static constexpr size_t QKV_STRIDE = (size_t)Bc * Hc * Tc * Dc; // 4194304
static constexpr float NEG_BIG = -3.0e38f;

__device__ __forceinline__ bf16x8 load8(const __hip_bfloat16* p) {
    return *(const bf16x8*)p;
}

__device__ __forceinline__ bf16x8 load8_lds(const __hip_bfloat16* p) {
    const bf16x4 lo = *(const bf16x4*)p;
    const bf16x4 hi = *(const bf16x4*)(p + 4);
    bf16x8 r;
    r[0] = lo[0]; r[1] = lo[1]; r[2] = lo[2]; r[3] = lo[3];
    r[4] = hi[0]; r[5] = hi[1]; r[6] = hi[2]; r[7] = hi[3];
    return r;
}

__device__ __forceinline__ short f2b(float x) {
    union { __hip_bfloat16 h; short s; } u;
    u.h = __float2bfloat16(x);
    return u.s;
}

// Pack two aligned float4s into a bf16x8 MFMA fragment.
__device__ __forceinline__ bf16x8 pack8(floatx4 a, floatx4 b) {
    bf16x8 r;
    r[0] = f2b(a[0]); r[1] = f2b(a[1]); r[2] = f2b(a[2]); r[3] = f2b(a[3]);
    r[4] = f2b(b[0]); r[5] = f2b(b[1]); r[6] = f2b(b[2]); r[7] = f2b(b[3]);
    return r;
}

// Async 16B global -> LDS (wave-uniform LDS base + lane*16).
__device__ __forceinline__ void gl2lds16(const void* g, void* l) {
    __builtin_amdgcn_global_load_lds(
        (const __attribute__((address_space(1))) void*)g,
        (__attribute__((address_space(3))) void*)l, 16, 0, 0);
}

// ================= GEMM1: qkv = x @ w_qkv^T, scatter to q/k/v ===============
// A = x f32 [4096,1024], W = w_qkv f32 [3072,1024]. Tile 128x128, BK=32.
// LDS f32 tiles, chunk(16B=4 f32) stored at position cg ^ (row&7): the
// ds_read_b128 fragment reads then land 2-way (free) instead of 16-way.
__global__ __launch_bounds__(256) void gemm_qkv(
    const float* __restrict__ A,
    const float* __restrict__ W,
    __hip_bfloat16* __restrict__ qkv) {
    __shared__ float As[128 * 32];
    __shared__ float Bs[128 * 32];
    const int K = Cc;
    const int lane = threadIdx.x & 63;
    const int wave = threadIdx.x >> 6;
    const int waveM = wave >> 1, waveN = wave & 1;
    const int mBase = blockIdx.x * 128;
    const int nBase = blockIdx.y * 128;
    const int idx16 = lane & 15;
    const int quad = lane >> 4;

    // staging coords (per global_load_lds instruction: 8 rows x 8 chunks)
    const int ldRow = lane >> 3;     // 0..7
    const int ldPos = lane & 7;      // stored chunk position

    floatx4 acc[4][4] = {};

    for (int k0 = 0; k0 < K; k0 += 32) {
        __syncthreads();
#pragma unroll
        for (int s = 0; s < 4; s++) {
            const int r0 = wave * 32 + s * 8;
            const int row = r0 + ldRow;
            const int cg = ldPos ^ (row & 7);          // swizzled source chunk
            gl2lds16(A + (size_t)(mBase + row) * K + k0 + cg * 4, &As[r0 * 32]);
            gl2lds16(W + (size_t)(nBase + row) * K + k0 + cg * 4, &Bs[r0 * 32]);
        }
        __syncthreads();

        bf16x8 af[4], bf[4];
#pragma unroll
        for (int i = 0; i < 4; i++) {
            const int rr = waveM * 64 + i * 16 + idx16;
            const floatx4 a0 = *(const floatx4*)&As[rr * 32 + (((quad * 2) ^ (rr & 7)) * 4)];
            const floatx4 a1 = *(const floatx4*)&As[rr * 32 + (((quad * 2 + 1) ^ (rr & 7)) * 4)];
            af[i] = pack8(a0, a1);
        }
#pragma unroll
        for (int j = 0; j < 4; j++) {
            const int rr = waveN * 64 + j * 16 + idx16;
            const floatx4 b0 = *(const floatx4*)&Bs[rr * 32 + (((quad * 2) ^ (rr & 7)) * 4)];
            const floatx4 b1 = *(const floatx4*)&Bs[rr * 32 + (((quad * 2 + 1) ^ (rr & 7)) * 4)];
            bf[j] = pack8(b0, b1);
        }
#pragma unroll
        for (int i = 0; i < 4; i++)
#pragma unroll
            for (int j = 0; j < 4; j++)
                acc[i][j] = MFMA16(af[i], bf[j], acc[i][j]);
    }

    // Epilogue: scatter C[m][n] -> qkv[part][b,h,t,d] (validated R7)
#pragma unroll
    for (int i = 0; i < 4; i++) {
#pragma unroll
        for (int j = 0; j < 4; j++) {
            const int n = nBase + waveN * 64 + j * 16 + idx16;
            const int part = n >> 10;
            const int rem = n & 1023;
            const int h = rem >> 6, d = rem & 63;
#pragma unroll
            for (int r = 0; r < 4; r++) {
                const int m = mBase + waveM * 64 + i * 16 + quad * 4 + r;
                const int bb = m >> 11, t = m & 2047;
                const size_t o = (size_t)part * QKV_STRIDE +
                                 (((size_t)(bb * Hc + h)) * Tc + t) * Dc + d;
                qkv[o] = __float2bfloat16(acc[i][j][r]);
            }
        }
    }
}

// ================= GEMM2: out(f32) = attn_out(bf16) @ w_proj^T(f32) =========
// Tile 128(m) x 64(n), BK=32, 512 blocks. A tile bf16 (swizzle &3), W f32 (&7).
__global__ __launch_bounds__(256) void gemm_proj(
    const __hip_bfloat16* __restrict__ A,
    const float* __restrict__ W,
    float* __restrict__ out) {
    __shared__ __hip_bfloat16 As16[128 * 32];
    __shared__ float Ws[64 * 32];
    const int K = Cc;
    const int lane = threadIdx.x & 63;
    const int wave = threadIdx.x >> 6;
    const int waveM = wave >> 1, waveN = wave & 1;
    const int mBase = blockIdx.x * 128;
    const int nBase = blockIdx.y * 64;
    const int idx16 = lane & 15;
    const int quad = lane >> 4;

    // bf16 staging: 16 rows x 4 chunks per instruction
    const int aRow = lane >> 2, aPos = lane & 3;
    // f32 staging: 8 rows x 8 chunks per instruction
    const int wRow = lane >> 3, wPos = lane & 7;

    floatx4 acc[4][2] = {};

    for (int k0 = 0; k0 < K; k0 += 32) {
        __syncthreads();
#pragma unroll
        for (int s = 0; s < 2; s++) {
            {   // A: 128 rows bf16, wave stages 32 rows (2 x 16)
                const int r0 = wave * 32 + s * 16;
                const int row = r0 + aRow;
                const int cg = aPos ^ (row & 3);
                gl2lds16(A + (size_t)(mBase + row) * K + k0 + cg * 8, &As16[r0 * 32]);
            }
            {   // W: 64 rows f32, wave stages 16 rows (2 x 8)
                const int r0 = wave * 16 + s * 8;
                const int row = r0 + wRow;
                const int cg = wPos ^ (row & 7);
                gl2lds16(W + (size_t)(nBase + row) * K + k0 + cg * 4, &Ws[r0 * 32]);
            }
        }
        __syncthreads();

        bf16x8 af[4], bf[2];
#pragma unroll
        for (int i = 0; i < 4; i++) {
            const int rr = waveM * 64 + i * 16 + idx16;
            af[i] = *(const bf16x8*)&As16[rr * 32 + ((quad ^ (rr & 3)) * 8)];
        }
#pragma unroll
        for (int j = 0; j < 2; j++) {
            const int rr = waveN * 32 + j * 16 + idx16;
            const floatx4 b0 = *(const floatx4*)&Ws[rr * 32 + (((quad * 2) ^ (rr & 7)) * 4)];
            const floatx4 b1 = *(const floatx4*)&Ws[rr * 32 + (((quad * 2 + 1) ^ (rr & 7)) * 4)];
            bf[j] = pack8(b0, b1);
        }
#pragma unroll
        for (int i = 0; i < 4; i++)
#pragma unroll
            for (int j = 0; j < 2; j++)
                acc[i][j] = MFMA16(af[i], bf[j], acc[i][j]);
    }

#pragma unroll
    for (int i = 0; i < 4; i++) {
#pragma unroll
        for (int j = 0; j < 2; j++) {
            const int n = nBase + waveN * 32 + j * 16 + idx16;
#pragma unroll
            for (int r = 0; r < 4; r++) {
                const int m = mBase + waveM * 64 + i * 16 + quad * 4 + r;
                out[(size_t)m * Cc + n] = acc[i][j][r];
            }
        }
    }
}

// ================= Flash attention (unchanged, R7-validated) ================
__global__ __launch_bounds__(256) void attn_kernel(
    const __hip_bfloat16* __restrict__ qkv,
    __hip_bfloat16* __restrict__ aout) {
    __shared__ __hip_bfloat16 lds_p[4][16][72];
    __shared__ __hip_bfloat16 lds_vt[64][72];

    const int lane = threadIdx.x & 63;
    const int wave = threadIdx.x >> 6;
    const int col = lane & 15;
    const int quad = lane >> 4;
    const int qt = blockIdx.x;
    const int h = blockIdx.y;
    const int b = blockIdx.z;
    const int qBase = qt * 64;

    const size_t headOff = ((size_t)(b * Hc + h)) * Tc * Dc;
    const __hip_bfloat16* qp = qkv + headOff;
    const __hip_bfloat16* kp = qkv + QKV_STRIDE + headOff;
    const __hip_bfloat16* vp = qkv + 2 * QKV_STRIDE + headOff;

    const int qrow = qBase + wave * 16 + col;
    bf16x8 qf[2];
    qf[0] = load8(qp + (size_t)qrow * Dc + quad * 8);
    qf[1] = load8(qp + (size_t)qrow * Dc + 32 + quad * 8);

    floatx4 o_acc[4] = {};
    float mrow[4], lrow[4];
#pragma unroll
    for (int r = 0; r < 4; r++) { mrow[r] = NEG_BIG; lrow[r] = 0.f; }
    const float scale = 0.125f;
    const int q0 = qBase + wave * 16 + quad * 4;

    const int nkt = qt + 1;
    for (int kt = 0; kt < nkt; kt++) {
        const int keyBase = kt * 64;

        __syncthreads();
#pragma unroll
        for (int i = 0; i < 16; i++) {
            const int e = i * 256 + threadIdx.x;
            const int kl = e >> 6, d = e & 63;
            lds_vt[d][kl] = vp[((size_t)(keyBase + kl)) * Dc + d];
        }
        __syncthreads();

        floatx4 s[4];
#pragma unroll
        for (int j = 0; j < 4; j++) {
            floatx4 acc = {0.f, 0.f, 0.f, 0.f};
            const int key = keyBase + j * 16 + col;
            const bf16x8 k0 = load8(kp + (size_t)key * Dc + quad * 8);
            const bf16x8 k1 = load8(kp + (size_t)key * Dc + 32 + quad * 8);
            acc = MFMA16(qf[0], k0, acc);
            acc = MFMA16(qf[1], k1, acc);
            s[j] = acc;
        }

        float pm[4];
#pragma unroll
        for (int r = 0; r < 4; r++) pm[r] = NEG_BIG;
#pragma unroll
        for (int j = 0; j < 4; j++) {
            const int key = keyBase + j * 16 + col;
#pragma unroll
            for (int r = 0; r < 4; r++) {
                float v = s[j][r] * scale;
                if (key > q0 + r) v = NEG_BIG;
                s[j][r] = v;
                pm[r] = fmaxf(pm[r], v);
            }
        }
#pragma unroll
        for (int off = 1; off < 16; off <<= 1)
#pragma unroll
            for (int r = 0; r < 4; r++)
                pm[r] = fmaxf(pm[r], __shfl_xor(pm[r], off, 64));

        float alpha[4];
#pragma unroll
        for (int r = 0; r < 4; r++) {
            const float mnew = fmaxf(mrow[r], pm[r]);
            alpha[r] = __expf(mrow[r] - mnew);
            mrow[r] = mnew;
        }

        float ps[4];
#pragma unroll
        for (int r = 0; r < 4; r++) ps[r] = 0.f;
#pragma unroll
        for (int j = 0; j < 4; j++) {
#pragma unroll
            for (int r = 0; r < 4; r++) {
                const float p = __expf(s[j][r] - mrow[r]);
                ps[r] += p;
                lds_p[wave][quad * 4 + r][j * 16 + col] = __float2bfloat16(p);
            }
        }
#pragma unroll
        for (int off = 1; off < 16; off <<= 1)
#pragma unroll
            for (int r = 0; r < 4; r++)
                ps[r] += __shfl_xor(ps[r], off, 64);
#pragma unroll
        for (int r = 0; r < 4; r++) lrow[r] = lrow[r] * alpha[r] + ps[r];
#pragma unroll
        for (int j = 0; j < 4; j++)
#pragma unroll
            for (int r = 0; r < 4; r++) o_acc[j][r] *= alpha[r];

        bf16x8 pf[2];
        pf[0] = load8_lds(&lds_p[wave][col][quad * 8]);
        pf[1] = load8_lds(&lds_p[wave][col][32 + quad * 8]);
#pragma unroll
        for (int j = 0; j < 4; j++) {
            const bf16x8 v0 = load8_lds(&lds_vt[j * 16 + col][quad * 8]);
            const bf16x8 v1 = load8_lds(&lds_vt[j * 16 + col][32 + quad * 8]);
            o_acc[j] = MFMA16(pf[0], v0, o_acc[j]);
            o_acc[j] = MFMA16(pf[1], v1, o_acc[j]);
        }
    }

#pragma unroll
    for (int j = 0; j < 4; j++) {
        const int d = j * 16 + col;
#pragma unroll
        for (int r = 0; r < 4; r++) {
            const int t = qBase + wave * 16 + quad * 4 + r;
            const size_t o = ((size_t)(b * Tc + t)) * Cc + h * 64 + d;
            aout[o] = __float2bfloat16(o_acc[j][r] / lrow[r]);
        }
    }
}

extern "C" void kernel_launch(void* const* d_in, const int* in_sizes, int n_in,
                              void* d_out, int out_size, void* d_ws, size_t ws_size,
                              hipStream_t stream) {
    const float* x = nullptr;
    const float* w_qkv = nullptr;
    const float* w_proj = nullptr;
    for (int i = 0; i < n_in; i++) {
        if (in_sizes[i] == 4194304) x = (const float*)d_in[i];
        else if (in_sizes[i] == 3145728) w_qkv = (const float*)d_in[i];
        else if (in_sizes[i] == 1048576) w_proj = (const float*)d_in[i];
    }
    float* out = (float*)d_out;

    __hip_bfloat16* qkv = (__hip_bfloat16*)d_ws;            // 3 * 4M bf16
    __hip_bfloat16* attn_out = qkv + 3 * QKV_STRIDE;        // 4M bf16

    gemm_qkv<<<dim3(4096 / 128, 3072 / 128), 256, 0, stream>>>(x, w_qkv, qkv);
    attn_kernel<<<dim3(Tc / 64, Hc, Bc), 256, 0, stream>>>(qkv, attn_out);
    gemm_proj<<<dim3(4096 / 128, 1024 / 64), 256, 0, stream>>>(attn_out, w_proj, out);
}